// Round 2
// baseline (3702.104 us; speedup 1.0000x reference)
//
#include <hip/hip_runtime.h>
#include <hip/hip_bf16.h>

typedef float f32x4 __attribute__((ext_vector_type(4)));
typedef __bf16 bf16x8 __attribute__((ext_vector_type(8)));

using as1c_t = __attribute__((address_space(1))) const char;
using as3_t  = __attribute__((address_space(3))) char;

static __device__ __forceinline__ float sigmoidf_(float x) {
  return 1.f / (1.f + __expf(-x));
}
static __device__ __forceinline__ __bf16 bfc(float x) { return (__bf16)x; }

// ---------------- K1: r = gather(hidden) @ W_red + b_red ----------------
// grid 256 (b, 8-group of n), block 256
__global__ __launch_bounds__(256) void k_r(const float* __restrict__ hidden,
    const float* __restrict__ Wred, const float* __restrict__ bred,
    const int* __restrict__ cidx, float* __restrict__ r) {
  __shared__ float docsT[768][8];
  const int bx = blockIdx.x;
  const int b = bx >> 3, n0 = (bx & 7) * 8;
  const int t = threadIdx.x;
  #pragma unroll
  for (int g = 0; g < 8; ++g) {
    const int tok = cidx[b * 64 + n0 + g];
    const float* src = hidden + ((size_t)b * 512 + tok) * 768;
    for (int f = t; f < 768; f += 256) docsT[f][g] = src[f];
  }
  __syncthreads();
  float acc[8];
  #pragma unroll
  for (int g = 0; g < 8; ++g) acc[g] = bred[t];
  for (int f = 0; f < 768; ++f) {
    const float w = Wred[f * 256 + t];
    const float4 d0 = *(const float4*)&docsT[f][0];
    const float4 d1 = *(const float4*)&docsT[f][4];
    acc[0] = fmaf(d0.x, w, acc[0]); acc[1] = fmaf(d0.y, w, acc[1]);
    acc[2] = fmaf(d0.z, w, acc[2]); acc[3] = fmaf(d0.w, w, acc[3]);
    acc[4] = fmaf(d1.x, w, acc[4]); acc[5] = fmaf(d1.y, w, acc[5]);
    acc[6] = fmaf(d1.z, w, acc[6]); acc[7] = fmaf(d1.w, w, acc[7]);
  }
  #pragma unroll
  for (int g = 0; g < 8; ++g) r[((size_t)(b * 64 + n0 + g)) * 256 + t] = acc[g];
}

// ---------------- K2: Ai = r@Wcat[:256] + b_cat ; Aj = r@Wcat[256:] ----------------
__global__ __launch_bounds__(256) void k_ab(const float* __restrict__ r,
    const float* __restrict__ Wcat, const float* __restrict__ bcat,
    float* __restrict__ Ai, float* __restrict__ Aj) {
  __shared__ float rT[256][8];
  const int bx = blockIdx.x;
  const int b = bx >> 3, n0 = (bx & 7) * 8;
  const int t = threadIdx.x;
  #pragma unroll
  for (int g = 0; g < 8; ++g)
    rT[t][g] = r[((size_t)(b * 64 + n0 + g)) * 256 + t];
  __syncthreads();
  float ai[8], aj[8];
  #pragma unroll
  for (int g = 0; g < 8; ++g) { ai[g] = bcat[t]; aj[g] = 0.f; }
  for (int k = 0; k < 256; ++k) {
    const float w0 = Wcat[k * 256 + t];
    const float w1 = Wcat[(256 + k) * 256 + t];
    const float4 d0 = *(const float4*)&rT[k][0];
    const float4 d1 = *(const float4*)&rT[k][4];
    ai[0] = fmaf(d0.x, w0, ai[0]); aj[0] = fmaf(d0.x, w1, aj[0]);
    ai[1] = fmaf(d0.y, w0, ai[1]); aj[1] = fmaf(d0.y, w1, aj[1]);
    ai[2] = fmaf(d0.z, w0, ai[2]); aj[2] = fmaf(d0.z, w1, aj[2]);
    ai[3] = fmaf(d0.w, w0, ai[3]); aj[3] = fmaf(d0.w, w1, aj[3]);
    ai[4] = fmaf(d1.x, w0, ai[4]); aj[4] = fmaf(d1.x, w1, aj[4]);
    ai[5] = fmaf(d1.y, w0, ai[5]); aj[5] = fmaf(d1.y, w1, aj[5]);
    ai[6] = fmaf(d1.z, w0, ai[6]); aj[6] = fmaf(d1.z, w1, aj[6]);
    ai[7] = fmaf(d1.w, w0, ai[7]); aj[7] = fmaf(d1.w, w1, aj[7]);
  }
  #pragma unroll
  for (int g = 0; g < 8; ++g) {
    Ai[((size_t)(b * 64 + n0 + g)) * 256 + t] = ai[g];
    Aj[((size_t)(b * 64 + n0 + g)) * 256 + t] = aj[g];
  }
}

// ---------------- K3: WxT[n][k] = bf16(W_x[k][n]) ----------------
__global__ __launch_bounds__(256) void k_wt(const float* __restrict__ Wx,
                                            __hip_bfloat16* __restrict__ WxT) {
  const int n = blockIdx.x, k = threadIdx.x;
  WxT[n * 256 + k] = __float2bfloat16(Wx[k * 768 + n]);
}

// ---------------- K4: xg = relu(Ai[i]+Aj[j]) @ W_x + b_g  (bf16 MFMA, fused A-tile) ----------------
// grid (Mg/128, 6), block 256 (4 waves, 2x2 of 64x64). Mg = group rows.
__global__ __launch_bounds__(256) void k_gemm(const float* __restrict__ Ai,
    const float* __restrict__ Aj, const __hip_bfloat16* __restrict__ WxT,
    const float* __restrict__ bg, __hip_bfloat16* __restrict__ xg,
    const int b_off) {
  __shared__ alignas(128) char smem[32768];  // A tile 16KB | B tile 16KB
  char* const smA = smem;
  char* const smB = smem + 16384;
  const int t = threadIdx.x;
  const int lane = t & 63, w = t >> 6;
  const int wr = w >> 1, wc = w & 1;
  const int m0 = blockIdx.x * 128;           // group-local row base
  const int n0 = blockIdx.y * 128;
  const char* const Wb = (const char*)WxT;

  // fused A-tile roles: thread t owns tile row rr = t>>1, half (32 cols) of K-step
  const int b = b_off + (m0 >> 12);
  const int ibase = (m0 >> 6) & 63;
  const int rr = t >> 1, half = t & 1;
  const int jj_ = rr & 63, ii_ = ibase + (rr >> 6);
  const float* const aiRow = Ai + ((size_t)b * 64 + ii_) * 256 + half * 32;
  const float* const ajRow = Aj + ((size_t)b * 64 + jj_) * 256 + half * 32;
  char* const dstA = smA + rr * 128 + half * 64;

  f32x4 acc[4][4];
  const f32x4 zero = {0.f, 0.f, 0.f, 0.f};
  #pragma unroll
  for (int a2 = 0; a2 < 4; ++a2)
    #pragma unroll
    for (int b2 = 0; b2 < 4; ++b2) acc[a2][b2] = zero;

  for (int s = 0; s < 4; ++s) {   // K-steps of 64 (K=256)
    const int k0 = s * 64;        // floats
    // A tile: X = relu(Ai + Aj) -> bf16 -> LDS (rows of 128B)
    #pragma unroll
    for (int q = 0; q < 4; ++q) {
      const float4 a0 = *(const float4*)(aiRow + k0 + q * 8);
      const float4 a1 = *(const float4*)(aiRow + k0 + q * 8 + 4);
      const float4 c0 = *(const float4*)(ajRow + k0 + q * 8);
      const float4 c1 = *(const float4*)(ajRow + k0 + q * 8 + 4);
      bf16x8 v;
      v[0] = bfc(fmaxf(a0.x + c0.x, 0.f)); v[1] = bfc(fmaxf(a0.y + c0.y, 0.f));
      v[2] = bfc(fmaxf(a0.z + c0.z, 0.f)); v[3] = bfc(fmaxf(a0.w + c0.w, 0.f));
      v[4] = bfc(fmaxf(a1.x + c1.x, 0.f)); v[5] = bfc(fmaxf(a1.y + c1.y, 0.f));
      v[6] = bfc(fmaxf(a1.z + c1.z, 0.f)); v[7] = bfc(fmaxf(a1.w + c1.w, 0.f));
      *(bf16x8*)(dstA + q * 16) = v;
    }
    // B tile via async global->LDS (16 chunks of 1KB)
    #pragma unroll
    for (int q = 0; q < 4; ++q) {
      const int chunk = w * 4 + q;
      const int tt2 = chunk * 1024 + lane * 16;
      const int row = tt2 >> 7;             // 0..127
      const int kb = tt2 & 0x7f;            // byte within 128B row
      __builtin_amdgcn_global_load_lds(
          (as1c_t*)(Wb + (size_t)(n0 + row) * 512 + s * 128 + kb),
          (as3_t*)(smB + chunk * 1024), 16, 0, 0);
    }
    __syncthreads();
    #pragma unroll
    for (int kk = 0; kk < 2; ++kk) {
      bf16x8 af[4], bfr[4];
      const int kloc = kk * 64 + ((lane >> 4) << 4);   // byte offset in row
      #pragma unroll
      for (int ft = 0; ft < 4; ++ft) {
        const int rowa = wr * 64 + ft * 16 + (lane & 15);
        af[ft] = *(const bf16x8*)(smA + rowa * 128 + kloc);
      }
      #pragma unroll
      for (int fn = 0; fn < 4; ++fn) {
        const int rowb = wc * 64 + fn * 16 + (lane & 15);
        bfr[fn] = *(const bf16x8*)(smB + rowb * 128 + kloc);
      }
      #pragma unroll
      for (int ft = 0; ft < 4; ++ft)
        #pragma unroll
        for (int fn = 0; fn < 4; ++fn)
          acc[ft][fn] = __builtin_amdgcn_mfma_f32_16x16x32_bf16(
              af[ft], bfr[fn], acc[ft][fn], 0, 0, 0);
    }
    __syncthreads();
  }

  #pragma unroll
  for (int ft = 0; ft < 4; ++ft) {
    const int mbase = m0 + wr * 64 + ft * 16 + ((lane >> 4) << 2);
    #pragma unroll
    for (int fn = 0; fn < 4; ++fn) {
      const int n = n0 + wc * 64 + fn * 16 + (lane & 15);
      const float bias = bg[n];
      #pragma unroll
      for (int jj = 0; jj < 4; ++jj)
        xg[(size_t)(mbase + jj) * 768 + n] = __float2bfloat16(acc[ft][fn][jj] + bias);
    }
  }
}

// ---------------- K5: one anti-diagonal of the 2-D GRU recurrence ----------------
// grid (L, Bg/8): cell (i, j=d-i) x 8-batch group; block 256 (one thread per H-col)
__global__ __launch_bounds__(256) void k_diag(const int d, const int ilo,
    const int b_off, const __hip_bfloat16* __restrict__ xg,
    const float* __restrict__ Uzr, const float* __restrict__ Ush,
    const float* __restrict__ Sr, float* __restrict__ Sw,
    const float* __restrict__ Wt, const float* __restrict__ bt,
    const int* __restrict__ ym,
    float* __restrict__ couples, float* __restrict__ diagbuf) {
  __shared__ float sp[256][8];
  __shared__ float rs[256][8];
  __shared__ float red[4][16];
  const int t = threadIdx.x;
  const int i = ilo + blockIdx.x;
  const int j = d - i;
  const int b0 = b_off + blockIdx.y * 8;

  // phase 0: s_prev = 0.5*(s_left + s_up); stored [k][bb]
  #pragma unroll
  for (int bb = 0; bb < 8; ++bb) {
    const int b = b0 + bb;
    const size_t base = ((size_t)(b * 64 + i)) * 256 + t;
    const float sl = (j > 0) ? Sr[base] : 0.f;         // cell (i, j-1): slot i
    const float su = (i > 0) ? Sr[base - 256] : 0.f;   // cell (i-1, j): slot i-1
    sp[t][bb] = 0.5f * (sl + su);
  }
  __syncthreads();

  // phase 1: z,r = sigmoid(xg[:512] + s_prev @ Us_zr); thread owns cols c, c+256
  const int c = t;
  float accz[8], accr[8];
  #pragma unroll
  for (int bb = 0; bb < 8; ++bb) {
    const size_t xrow = ((size_t)(b0 + bb - b_off) * 4096 + (size_t)i * 64 + j) * 768;
    accz[bb] = __bfloat162float(xg[xrow + c]);
    accr[bb] = __bfloat162float(xg[xrow + 256 + c]);
  }
  for (int k = 0; k < 256; ++k) {
    const float w0 = Uzr[k * 512 + c];
    const float w1 = Uzr[k * 512 + 256 + c];
    const float4 s0 = *(const float4*)&sp[k][0];
    const float4 s1 = *(const float4*)&sp[k][4];
    accz[0] = fmaf(s0.x, w0, accz[0]); accr[0] = fmaf(s0.x, w1, accr[0]);
    accz[1] = fmaf(s0.y, w0, accz[1]); accr[1] = fmaf(s0.y, w1, accr[1]);
    accz[2] = fmaf(s0.z, w0, accz[2]); accr[2] = fmaf(s0.z, w1, accr[2]);
    accz[3] = fmaf(s0.w, w0, accz[3]); accr[3] = fmaf(s0.w, w1, accr[3]);
    accz[4] = fmaf(s1.x, w0, accz[4]); accr[4] = fmaf(s1.x, w1, accr[4]);
    accz[5] = fmaf(s1.y, w0, accz[5]); accr[5] = fmaf(s1.y, w1, accr[5]);
    accz[6] = fmaf(s1.z, w0, accz[6]); accr[6] = fmaf(s1.z, w1, accr[6]);
    accz[7] = fmaf(s1.w, w0, accz[7]); accr[7] = fmaf(s1.w, w1, accr[7]);
  }
  float zv[8];
  #pragma unroll
  for (int bb = 0; bb < 8; ++bb) {
    zv[bb] = sigmoidf_(accz[bb]);
    const float rr = sigmoidf_(accr[bb]);
    rs[c][bb] = rr * sp[c][bb];
  }
  __syncthreads();

  // phase 2: h = tanh(xg[512:] + (r*s_prev) @ Us_h); update; fused couples proj
  float acch[8];
  #pragma unroll
  for (int bb = 0; bb < 8; ++bb) {
    const size_t xrow = ((size_t)(b0 + bb - b_off) * 4096 + (size_t)i * 64 + j) * 768;
    acch[bb] = __bfloat162float(xg[xrow + 512 + c]);
  }
  for (int k = 0; k < 256; ++k) {
    const float w = Ush[k * 256 + c];
    const float4 r0 = *(const float4*)&rs[k][0];
    const float4 r1 = *(const float4*)&rs[k][4];
    acch[0] = fmaf(r0.x, w, acch[0]); acch[1] = fmaf(r0.y, w, acch[1]);
    acch[2] = fmaf(r0.z, w, acch[2]); acch[3] = fmaf(r0.w, w, acch[3]);
    acch[4] = fmaf(r1.x, w, acch[4]); acch[5] = fmaf(r1.y, w, acch[5]);
    acch[6] = fmaf(r1.z, w, acch[6]); acch[7] = fmaf(r1.w, w, acch[7]);
  }
  float cp[16];
  #pragma unroll
  for (int bb = 0; bb < 8; ++bb) {
    const int b = b0 + bb;
    const float h = tanhf(acch[bb]);
    const float spv = sp[c][bb];
    float sv = (1.f - zv[bb]) * spv + zv[bb] * h;
    sv *= (float)(ym[b * 64 + i] & ym[b * 64 + j]);
    Sw[((size_t)(b * 64 + i)) * 256 + c] = sv;
    if (i == j) diagbuf[((size_t)(b * 64 + i)) * 256 + c] = sv;
    cp[bb * 2 + 0] = sv * Wt[c * 2 + 0];
    cp[bb * 2 + 1] = sv * Wt[c * 2 + 1];
  }
  #pragma unroll
  for (int v = 0; v < 16; ++v) {
    float x = cp[v];
    x += __shfl_xor(x, 1);  x += __shfl_xor(x, 2);  x += __shfl_xor(x, 4);
    x += __shfl_xor(x, 8);  x += __shfl_xor(x, 16); x += __shfl_xor(x, 32);
    cp[v] = x;
  }
  if ((t & 63) == 0) {
    #pragma unroll
    for (int v = 0; v < 16; ++v) red[t >> 6][v] = cp[v];
  }
  __syncthreads();
  if (t < 16) {
    const float x = red[0][t] + red[1][t] + red[2][t] + red[3][t];
    const int bb = t >> 1, o = t & 1;
    couples[(((size_t)(b0 + bb) * 4096) + (size_t)i * 64 + j) * 2 + o] = x + bt[o];
  }
}

// ---------------- K6: pred_e / pred_c from diagonal states ----------------
__global__ __launch_bounds__(256) void k_head(const float* __restrict__ diagbuf,
    const float* __restrict__ We, const float* __restrict__ be,
    const float* __restrict__ Wc, const float* __restrict__ bc,
    float* __restrict__ pe, float* __restrict__ pc) {
  __shared__ float red[4][4];
  const int bn = blockIdx.x;
  const int t = threadIdx.x;
  const float s = diagbuf[(size_t)bn * 256 + t];
  float v[4] = { s * We[t * 2], s * We[t * 2 + 1], s * Wc[t * 2], s * Wc[t * 2 + 1] };
  #pragma unroll
  for (int q = 0; q < 4; ++q) {
    float x = v[q];
    x += __shfl_xor(x, 1);  x += __shfl_xor(x, 2);  x += __shfl_xor(x, 4);
    x += __shfl_xor(x, 8);  x += __shfl_xor(x, 16); x += __shfl_xor(x, 32);
    v[q] = x;
  }
  if ((t & 63) == 0) {
    #pragma unroll
    for (int q = 0; q < 4; ++q) red[t >> 6][q] = v[q];
  }
  __syncthreads();
  if (t < 4) {
    const float x = red[0][t] + red[1][t] + red[2][t] + red[3][t];
    if (t < 2) pe[bn * 2 + t] = x + be[t];
    else       pc[bn * 2 + (t - 2)] = x + bc[t - 2];
  }
}

extern "C" void kernel_launch(void* const* d_in, const int* in_sizes, int n_in,
                              void* d_out, int out_size, void* d_ws, size_t ws_size,
                              hipStream_t stream) {
  const float* hidden = (const float*)d_in[0];
  const float* Wred = (const float*)d_in[1];
  const float* bred = (const float*)d_in[2];
  const float* Wcat = (const float*)d_in[3];
  const float* bcat = (const float*)d_in[4];
  const float* Wx   = (const float*)d_in[5];
  const float* Uzr  = (const float*)d_in[6];
  const float* Ush  = (const float*)d_in[7];
  const float* bg   = (const float*)d_in[8];
  const float* We   = (const float*)d_in[9];
  const float* be   = (const float*)d_in[10];
  const float* Wc   = (const float*)d_in[11];
  const float* bc   = (const float*)d_in[12];
  const float* Wt   = (const float*)d_in[13];
  const float* bt   = (const float*)d_in[14];
  const int* cidx   = (const int*)d_in[15];
  const int* ym     = (const int*)d_in[16];

  // ---- workspace layout: small buffers first, xg chunk last ----
  char* ws = (char*)d_ws;
  const size_t MB2 = 2097152;
  float* r    = (float*)(ws);                  // 2 MB
  float* Ai   = (float*)(ws + 1 * MB2);        // 2 MB
  float* Aj   = (float*)(ws + 2 * MB2);        // 2 MB
  float* diag = (float*)(ws + 3 * MB2);        // 2 MB
  float* S0   = (float*)(ws + 4 * MB2);        // 2 MB
  float* S1   = (float*)(ws + 5 * MB2);        // 2 MB
  __hip_bfloat16* WxT = (__hip_bfloat16*)(ws + 6 * MB2);      // 393216 B
  const size_t xg_off = 6 * MB2 + 393216;                     // 12,976,128
  __hip_bfloat16* xg  = (__hip_bfloat16*)(ws + xg_off);

  // batch-group count: largest xg chunk that fits ws_size
  const size_t XG_FULL = (size_t)131072 * 768 * 2;            // 201,326,592
  int g = 4;
  if (ws_size >= xg_off + XG_FULL) g = 1;
  else if (ws_size >= xg_off + XG_FULL / 2) g = 2;
  const int Bg = 32 / g;
  const int Mg = Bg * 4096;

  float* couples = (float*)d_out;          // (32,64,64,2)
  float* pe = couples + 262144;            // (32,64,2)
  float* pc = couples + 266240;            // (32,64,2)

  k_r<<<256, 256, 0, stream>>>(hidden, Wred, bred, cidx, r);
  k_ab<<<256, 256, 0, stream>>>(r, Wcat, bcat, Ai, Aj);
  k_wt<<<768, 256, 0, stream>>>(Wx, WxT);

  for (int grp = 0; grp < g; ++grp) {
    const int b_off = grp * Bg;
    k_gemm<<<dim3(Mg / 128, 6), 256, 0, stream>>>(Ai, Aj, WxT, bg, xg, b_off);
    for (int d = 0; d < 127; ++d) {
      const int ilo = d > 63 ? d - 63 : 0;
      const int ihi = d < 63 ? d : 63;
      const int L = ihi - ilo + 1;
      const float* Srd = (d & 1) ? S0 : S1;
      float* Swr = (d & 1) ? S1 : S0;
      k_diag<<<dim3(L, Bg / 8), 256, 0, stream>>>(d, ilo, b_off, xg, Uzr, Ush,
                                                  Srd, Swr, Wt, bt, ym,
                                                  couples, diag);
    }
  }
  k_head<<<2048, 256, 0, stream>>>(diag, We, be, Wc, bc, pe, pc);
}